// Round 12
// baseline (56.475 us; speedup 1.0000x reference)
//
#include <hip/hip_runtime.h>
#include <math.h>

typedef _Float16 half8 __attribute__((ext_vector_type(8)));
typedef float f32x4 __attribute__((ext_vector_type(4)));

namespace {
constexpr int kB = 65536;      // rows
constexpr int kC = 300;        // cards/options dim
constexpr int kA = 32;         // archetype dim
constexpr int kBlock = 512;    // 8 waves
constexpr int kRowsPerBlock = 128;  // 16 rows per wave -> grid 512 = 2 blocks/CU exactly
constexpr int kWTS = 328;      // f16 stride of W^T tile [32][328]; bank-quad step 16B -> clean
constexpr int kWrS = 40;       // f16 stride of W row tile [304][40]
constexpr int kApS = 40;       // per-wave ap tile stride
}

// DPP row_ror reductions within each 16-lane DPP row (quarter-wave == C-tile row group).
template <int kCtrl>
__device__ __forceinline__ float dpp_rot(float x) {
    int yi = __builtin_amdgcn_update_dpp(0, __builtin_bit_cast(int, x), kCtrl, 0xf, 0xf, false);
    return __builtin_bit_cast(float, yi);
}
__device__ __forceinline__ float rsum16(float x) {
    x += dpp_rot<0x128>(x);
    x += dpp_rot<0x124>(x);
    x += dpp_rot<0x122>(x);
    x += dpp_rot<0x121>(x);
    return x;
}
__device__ __forceinline__ float rmax16(float x) {
    x = fmaxf(x, dpp_rot<0x128>(x));
    x = fmaxf(x, dpp_rot<0x124>(x));
    x = fmaxf(x, dpp_rot<0x122>(x));
    x = fmaxf(x, dpp_rot<0x121>(x));
    return x;
}

__global__ __launch_bounds__(kBlock) void draftbot_kernel(
    const float* __restrict__ X,
    const float* __restrict__ W,
    float* __restrict__ out)
{
    __shared__ _Float16 WT[kA * kWTS];       // W^T  [a][c], c-pads zeroed   20,992 B
    __shared__ _Float16 Wr[304 * kWrS];      // W    [c][a], row-pads zeroed 24,320 B
    __shared__ _Float16 ap_s[8][16 * kApS];  // per-wave ap tile [m][a]      10,240 B

    const int tid  = threadIdx.x;
    const int lane = tid & 63;
    const int wid  = tid >> 6;
    const int lm = lane & 15;        // M/N index within fragment
    const int lq = lane >> 4;        // quarter-wave
    const int ko = lq * 8;           // K offset within 32-chunk
    const size_t r0 = (size_t)blockIdx.x * kRowsPerBlock + wid * 16;

    // ---- option bits (4 u32/lane): obit[j] bit n = options[r0+4*lq+j][16n+lm] != 0.
    //      Quarter-wave reads 64B lines; issued first so latency hides under staging.
    unsigned int obit[4];
    #pragma unroll
    for (int j = 0; j < 4; ++j) {
        const float* __restrict__ ox = X + (r0 + 4 * lq + j) * (size_t)(2 * kC);
        unsigned int b = 0;
        #pragma unroll
        for (int n = 0; n < 19; ++n) {
            const int c = 16 * n + lm;
            if (c < kC && ox[c] != 0.0f) b |= (1u << n);
        }
        obit[j] = b;
    }

    // ---- stage W into both LDS layouts (f16), coalesced f32 reads ----
    for (int e = tid; e < kC * kA; e += kBlock) {
        const int c = e >> 5;
        const int a = e & 31;
        const _Float16 h = (_Float16)W[e];
        WT[a * kWTS + c] = h;
        Wr[c * kWrS + a] = h;
    }
    for (int e = tid; e < kA * (kWTS - kC); e += kBlock) {      // zero WT c-pads (300..327)
        const int a = e / (kWTS - kC);
        const int c = kC + e % (kWTS - kC);
        WT[a * kWTS + c] = (_Float16)0.0f;
    }
    if (tid < 4 * kWrS) Wr[kC * kWrS + tid] = (_Float16)0.0f;   // zero Wr rows 300..303
    __syncthreads();

    // ---- GEMM1: ap(16x32) = cards(16x300) @ W(300x32); A from global, B from WT ----
    const float* __restrict__ crow = X + (r0 + lm) * (size_t)(2 * kC) + kC;
    f32x4 acc0 = {0.f, 0.f, 0.f, 0.f};
    f32x4 acc1 = {0.f, 0.f, 0.f, 0.f};
    #pragma unroll
    for (int s = 0; s < 9; ++s) {   // K = 0..287
        const float4 u = *reinterpret_cast<const float4*>(crow + 32 * s + ko);
        const float4 v = *reinterpret_cast<const float4*>(crow + 32 * s + ko + 4);
        const half8 Af = { (_Float16)u.x, (_Float16)u.y, (_Float16)u.z, (_Float16)u.w,
                           (_Float16)v.x, (_Float16)v.y, (_Float16)v.z, (_Float16)v.w };
        const half8 B0 = *reinterpret_cast<const half8*>(&WT[lm * kWTS + 32 * s + ko]);
        const half8 B1 = *reinterpret_cast<const half8*>(&WT[(16 + lm) * kWTS + 32 * s + ko]);
        acc0 = __builtin_amdgcn_mfma_f32_16x16x32_f16(Af, B0, acc0, 0, 0, 0);
        acc1 = __builtin_amdgcn_mfma_f32_16x16x32_f16(Af, B1, acc1, 0, 0, 0);
    }
    {   // tail K = 288..299 (A zero-padded, WT pads are zero)
        float av[8];
        #pragma unroll
        for (int j = 0; j < 8; ++j) {
            const int k = 288 + ko + j;
            av[j] = (k < kC) ? crow[k] : 0.0f;
        }
        const half8 Af = { (_Float16)av[0], (_Float16)av[1], (_Float16)av[2], (_Float16)av[3],
                           (_Float16)av[4], (_Float16)av[5], (_Float16)av[6], (_Float16)av[7] };
        const half8 B0 = *reinterpret_cast<const half8*>(&WT[lm * kWTS + 288 + ko]);
        const half8 B1 = *reinterpret_cast<const half8*>(&WT[(16 + lm) * kWTS + 288 + ko]);
        acc0 = __builtin_amdgcn_mfma_f32_16x16x32_f16(Af, B0, acc0, 0, 0, 0);
        acc1 = __builtin_amdgcn_mfma_f32_16x16x32_f16(Af, B1, acc1, 0, 0, 0);
    }

    // ---- epilogue: ap = acc + 1 -> f16 -> per-wave LDS tile (intra-wave only) ----
    _Float16* __restrict__ aps = ap_s[wid];
    #pragma unroll
    for (int j = 0; j < 4; ++j) {
        const int rr = 4 * lq + j;              // C row = 4*(lane>>4) + reg
        aps[rr * kApS + lm]      = (_Float16)(acc0[j] + 1.0f);
        aps[rr * kApS + 16 + lm] = (_Float16)(acc1[j] + 1.0f);
    }
    asm volatile("s_waitcnt lgkmcnt(0)" ::: "memory");
    __builtin_amdgcn_sched_barrier(0);
    // GEMM2 A-fragment: ap[m = lm][k = ko..ko+7], reused by all 3 passes
    const half8 A2 = *reinterpret_cast<const half8*>(&aps[lm * kApS + ko]);

    const f32x4 zz = {0.f, 0.f, 0.f, 0.f};

    // ---- pass 1: row max (masked-off elements are 0 and participate, as in ref) ----
    f32x4 mj = {0.f, 0.f, 0.f, 0.f};   // every row has zeros (option density ~5%)
    #pragma unroll
    for (int n = 0; n < 19; ++n) {
        const half8 Bn = *reinterpret_cast<const half8*>(&Wr[(16 * n + lm) * kWrS + ko]);
        const f32x4 c4 = __builtin_amdgcn_mfma_f32_16x16x32_f16(A2, Bn, zz, 0, 0, 0);
        #pragma unroll
        for (int j = 0; j < 4; ++j) {
            const float x = ((obit[j] >> n) & 1u) ? c4[j] : 0.0f;
            mj[j] = fmaxf(mj[j], x);
        }
    }
    #pragma unroll
    for (int j = 0; j < 4; ++j) mj[j] = rmax16(mj[j]);

    // ---- pass 2: S = sum of s * exp(x - M*s) ----
    f32x4 Sj = {0.f, 0.f, 0.f, 0.f};
    #pragma unroll
    for (int n = 0; n < 19; ++n) {
        const half8 Bn = *reinterpret_cast<const half8*>(&Wr[(16 * n + lm) * kWrS + ko]);
        const f32x4 c4 = __builtin_amdgcn_mfma_f32_16x16x32_f16(A2, Bn, zz, 0, 0, 0);
        #pragma unroll
        for (int j = 0; j < 4; ++j) {
            const float x = ((obit[j] >> n) & 1u) ? c4[j] : 0.0f;
            const float sg = (x > 0.f ? 1.f : 0.f) - (x < 0.f ? 1.f : 0.f);
            Sj[j] += sg * __expf(fmaf(-mj[j], sg, x));
        }
    }
    f32x4 lse;
    #pragma unroll
    for (int j = 0; j < 4; ++j) lse[j] = __logf(rsum16(Sj[j]));

    // ---- pass 3: out = s * (x - M*s - lse) ----
    #pragma unroll
    for (int n = 0; n < 19; ++n) {
        const half8 Bn = *reinterpret_cast<const half8*>(&Wr[(16 * n + lm) * kWrS + ko]);
        const f32x4 c4 = __builtin_amdgcn_mfma_f32_16x16x32_f16(A2, Bn, zz, 0, 0, 0);
        const int c = 16 * n + lm;
        if (c < kC) {
            #pragma unroll
            for (int j = 0; j < 4; ++j) {
                const float x = ((obit[j] >> n) & 1u) ? c4[j] : 0.0f;
                const float sg = (x > 0.f ? 1.f : 0.f) - (x < 0.f ? 1.f : 0.f);
                out[(r0 + 4 * lq + j) * (size_t)kC + c] = sg * (fmaf(-mj[j], sg, x) - lse[j]);
            }
        }
    }
}

extern "C" void kernel_launch(void* const* d_in, const int* in_sizes, int n_in,
                              void* d_out, int out_size, void* d_ws, size_t ws_size,
                              hipStream_t stream) {
    const float* X = (const float*)d_in[0];
    const float* W = (const float*)d_in[1];
    float* out = (float*)d_out;
    dim3 grid(kB / kRowsPerBlock);   // 512 blocks = 2 blocks/CU x 256 CU, zero tail
    dim3 block(kBlock);              // 512 threads
    hipLaunchKernelGGL(draftbot_kernel, grid, block, 0, stream, X, W, out);
}

// Round 13
// 53.811 us; speedup vs baseline: 1.0495x; 1.0495x over previous
//
#include <hip/hip_runtime.h>
#include <math.h>

typedef _Float16 half8 __attribute__((ext_vector_type(8)));
typedef float f32x4 __attribute__((ext_vector_type(4)));

namespace {
constexpr int kB = 65536;      // rows
constexpr int kC = 300;        // cards/options dim
constexpr int kA = 32;         // archetype dim
constexpr int kBlock = 512;    // 8 waves
constexpr int kRowsPerBlock = 128;  // 16 rows per wave
constexpr int kWTS = 328;      // f16 stride of W^T tile [32][328]
constexpr int kWrS = 40;       // f16 stride of W row tile [304][40]
}

// DPP row_ror reductions within each 16-lane DPP row (quarter-wave == C-tile row group).
template <int kCtrl>
__device__ __forceinline__ float dpp_rot(float x) {
    int yi = __builtin_amdgcn_update_dpp(0, __builtin_bit_cast(int, x), kCtrl, 0xf, 0xf, false);
    return __builtin_bit_cast(float, yi);
}
__device__ __forceinline__ float rsum16(float x) {
    x += dpp_rot<0x128>(x);
    x += dpp_rot<0x124>(x);
    x += dpp_rot<0x122>(x);
    x += dpp_rot<0x121>(x);
    return x;
}
__device__ __forceinline__ float rmax16(float x) {
    x = fmaxf(x, dpp_rot<0x128>(x));
    x = fmaxf(x, dpp_rot<0x124>(x));
    x = fmaxf(x, dpp_rot<0x122>(x));
    x = fmaxf(x, dpp_rot<0x121>(x));
    return x;
}

// ---------------- Kernel A: ap[B][32] (f16) = cards @ W + 1 ----------------
__global__ __launch_bounds__(kBlock) void gemm1_kernel(
    const float* __restrict__ X,
    const float* __restrict__ W,
    _Float16* __restrict__ apws)
{
    __shared__ _Float16 WT[kA * kWTS];       // W^T [a][c], c-pads zeroed

    const int tid  = threadIdx.x;
    const int lane = tid & 63;
    const int wid  = tid >> 6;
    const int lm = lane & 15;
    const int lq = lane >> 4;
    const int ko = lq * 8;
    const size_t r0 = (size_t)blockIdx.x * kRowsPerBlock + wid * 16;

    // stage W^T (f16) + zero pads
    for (int e = tid; e < kC * kA; e += kBlock) {
        const int c = e >> 5;
        const int a = e & 31;
        WT[a * kWTS + c] = (_Float16)W[e];
    }
    for (int e = tid; e < kA * (kWTS - kC); e += kBlock) {
        const int a = e / (kWTS - kC);
        const int c = kC + e % (kWTS - kC);
        WT[a * kWTS + c] = (_Float16)0.0f;
    }
    __syncthreads();

    const float* __restrict__ crow = X + (r0 + lm) * (size_t)(2 * kC) + kC;
    f32x4 acc0 = {0.f, 0.f, 0.f, 0.f};
    f32x4 acc1 = {0.f, 0.f, 0.f, 0.f};
    #pragma unroll
    for (int s = 0; s < 9; ++s) {   // K = 0..287
        const float4 u = *reinterpret_cast<const float4*>(crow + 32 * s + ko);
        const float4 v = *reinterpret_cast<const float4*>(crow + 32 * s + ko + 4);
        const half8 Af = { (_Float16)u.x, (_Float16)u.y, (_Float16)u.z, (_Float16)u.w,
                           (_Float16)v.x, (_Float16)v.y, (_Float16)v.z, (_Float16)v.w };
        const half8 B0 = *reinterpret_cast<const half8*>(&WT[lm * kWTS + 32 * s + ko]);
        const half8 B1 = *reinterpret_cast<const half8*>(&WT[(16 + lm) * kWTS + 32 * s + ko]);
        acc0 = __builtin_amdgcn_mfma_f32_16x16x32_f16(Af, B0, acc0, 0, 0, 0);
        acc1 = __builtin_amdgcn_mfma_f32_16x16x32_f16(Af, B1, acc1, 0, 0, 0);
    }
    {   // tail K = 288..299 (A zero-padded, WT pads zero)
        float av[8];
        #pragma unroll
        for (int j = 0; j < 8; ++j) {
            const int k = 288 + ko + j;
            av[j] = (k < kC) ? crow[k] : 0.0f;
        }
        const half8 Af = { (_Float16)av[0], (_Float16)av[1], (_Float16)av[2], (_Float16)av[3],
                           (_Float16)av[4], (_Float16)av[5], (_Float16)av[6], (_Float16)av[7] };
        const half8 B0 = *reinterpret_cast<const half8*>(&WT[lm * kWTS + 288 + ko]);
        const half8 B1 = *reinterpret_cast<const half8*>(&WT[(16 + lm) * kWTS + 288 + ko]);
        acc0 = __builtin_amdgcn_mfma_f32_16x16x32_f16(Af, B0, acc0, 0, 0, 0);
        acc1 = __builtin_amdgcn_mfma_f32_16x16x32_f16(Af, B1, acc1, 0, 0, 0);
    }

    // ap = acc + 1 -> f16 -> global ws (row-major, 32 f16 = 64B per row)
    #pragma unroll
    for (int j = 0; j < 4; ++j) {
        const size_t base = (r0 + 4 * lq + j) * (size_t)kA;
        apws[base + lm]      = (_Float16)(acc0[j] + 1.0f);
        apws[base + 16 + lm] = (_Float16)(acc1[j] + 1.0f);
    }
}

// ------------- Kernel B: scores = ap @ W^T, masked log-softmax -------------
__global__ __launch_bounds__(kBlock) void gemm2_kernel(
    const float* __restrict__ X,
    const float* __restrict__ W,
    const _Float16* __restrict__ apws,
    float* __restrict__ out)
{
    __shared__ _Float16 Wr[304 * kWrS];      // W [c][a], pad rows zeroed

    const int tid  = threadIdx.x;
    const int lane = tid & 63;
    const int wid  = tid >> 6;
    const int lm = lane & 15;
    const int lq = lane >> 4;
    const int ko = lq * 8;
    const size_t r0 = (size_t)blockIdx.x * kRowsPerBlock + wid * 16;

    // A-fragment for GEMM2 straight from global ws: ap[r0+lm][ko..ko+7], 16B load.
    const half8 A2 = *reinterpret_cast<const half8*>(&apws[(r0 + lm) * (size_t)kA + ko]);

    // option bits (4 u32/lane), issued early so latency hides under staging
    unsigned int obit[4];
    #pragma unroll
    for (int j = 0; j < 4; ++j) {
        const float* __restrict__ ox = X + (r0 + 4 * lq + j) * (size_t)(2 * kC);
        unsigned int b = 0;
        #pragma unroll
        for (int n = 0; n < 19; ++n) {
            const int c = 16 * n + lm;
            if (c < kC && ox[c] != 0.0f) b |= (1u << n);
        }
        obit[j] = b;
    }

    // stage W rows (f16) + zero pad rows 300..303
    for (int e = tid; e < kC * kA; e += kBlock) {
        const int c = e >> 5;
        const int a = e & 31;
        Wr[c * kWrS + a] = (_Float16)W[e];
    }
    if (tid < 4 * kWrS) Wr[kC * kWrS + tid] = (_Float16)0.0f;
    __syncthreads();

    const f32x4 zz = {0.f, 0.f, 0.f, 0.f};

    // pass 1: row max (masked-off elements are 0 and participate, as in ref)
    f32x4 mj = {0.f, 0.f, 0.f, 0.f};   // every row has zeros (option density ~5%)
    #pragma unroll
    for (int n = 0; n < 19; ++n) {
        const half8 Bn = *reinterpret_cast<const half8*>(&Wr[(16 * n + lm) * kWrS + ko]);
        const f32x4 c4 = __builtin_amdgcn_mfma_f32_16x16x32_f16(A2, Bn, zz, 0, 0, 0);
        #pragma unroll
        for (int j = 0; j < 4; ++j) {
            const float x = ((obit[j] >> n) & 1u) ? c4[j] : 0.0f;
            mj[j] = fmaxf(mj[j], x);
        }
    }
    #pragma unroll
    for (int j = 0; j < 4; ++j) mj[j] = rmax16(mj[j]);

    // pass 2: S = sum of s * exp(x - M*s)
    f32x4 Sj = {0.f, 0.f, 0.f, 0.f};
    #pragma unroll
    for (int n = 0; n < 19; ++n) {
        const half8 Bn = *reinterpret_cast<const half8*>(&Wr[(16 * n + lm) * kWrS + ko]);
        const f32x4 c4 = __builtin_amdgcn_mfma_f32_16x16x32_f16(A2, Bn, zz, 0, 0, 0);
        #pragma unroll
        for (int j = 0; j < 4; ++j) {
            const float x = ((obit[j] >> n) & 1u) ? c4[j] : 0.0f;
            const float sg = (x > 0.f ? 1.f : 0.f) - (x < 0.f ? 1.f : 0.f);
            Sj[j] += sg * __expf(fmaf(-mj[j], sg, x));
        }
    }
    f32x4 lse;
    #pragma unroll
    for (int j = 0; j < 4; ++j) lse[j] = __logf(rsum16(Sj[j]));

    // pass 3: out = s * (x - M*s - lse)
    #pragma unroll
    for (int n = 0; n < 19; ++n) {
        const half8 Bn = *reinterpret_cast<const half8*>(&Wr[(16 * n + lm) * kWrS + ko]);
        const f32x4 c4 = __builtin_amdgcn_mfma_f32_16x16x32_f16(A2, Bn, zz, 0, 0, 0);
        const int c = 16 * n + lm;
        if (c < kC) {
            #pragma unroll
            for (int j = 0; j < 4; ++j) {
                const float x = ((obit[j] >> n) & 1u) ? c4[j] : 0.0f;
                const float sg = (x > 0.f ? 1.f : 0.f) - (x < 0.f ? 1.f : 0.f);
                out[(r0 + 4 * lq + j) * (size_t)kC + c] = sg * (fmaf(-mj[j], sg, x) - lse[j]);
            }
        }
    }
}

extern "C" void kernel_launch(void* const* d_in, const int* in_sizes, int n_in,
                              void* d_out, int out_size, void* d_ws, size_t ws_size,
                              hipStream_t stream) {
    const float* X = (const float*)d_in[0];
    const float* W = (const float*)d_in[1];
    float* out = (float*)d_out;
    _Float16* apws = (_Float16*)d_ws;        // 65536*32*2B = 4 MiB scratch
    dim3 grid(kB / kRowsPerBlock);           // 512 blocks
    dim3 block(kBlock);                      // 512 threads
    hipLaunchKernelGGL(gemm1_kernel, grid, block, 0, stream, X, W, apws);
    hipLaunchKernelGGL(gemm2_kernel, grid, block, 0, stream, X, W, apws, out);
}

// Round 14
// 52.430 us; speedup vs baseline: 1.0771x; 1.0263x over previous
//
#include <hip/hip_runtime.h>
#include <math.h>

typedef _Float16 half8 __attribute__((ext_vector_type(8)));
typedef float f32x4 __attribute__((ext_vector_type(4)));

namespace {
constexpr int kB = 65536;      // rows
constexpr int kC = 300;        // cards/options dim
constexpr int kA = 32;         // archetype dim
constexpr int kBlock = 512;    // 8 waves
constexpr int kRowsPerBlock = 128;  // 16 rows per wave
constexpr int kWTS = 328;      // f16 stride of W^T tile [32][328]
constexpr int kWrS = 40;       // f16 stride of W row tile [304][40]
}

// DPP row_ror reductions within each 16-lane DPP row (quarter-wave == C-tile row group).
template <int kCtrl>
__device__ __forceinline__ float dpp_rot(float x) {
    int yi = __builtin_amdgcn_update_dpp(0, __builtin_bit_cast(int, x), kCtrl, 0xf, 0xf, false);
    return __builtin_bit_cast(float, yi);
}
__device__ __forceinline__ float rsum16(float x) {
    x += dpp_rot<0x128>(x);
    x += dpp_rot<0x124>(x);
    x += dpp_rot<0x122>(x);
    x += dpp_rot<0x121>(x);
    return x;
}
__device__ __forceinline__ float rmax16(float x) {
    x = fmaxf(x, dpp_rot<0x128>(x));
    x = fmaxf(x, dpp_rot<0x124>(x));
    x = fmaxf(x, dpp_rot<0x122>(x));
    x = fmaxf(x, dpp_rot<0x121>(x));
    return x;
}

// -------- Kernel A: ap[B][32] (f16) = cards @ W + 1, plus option masks --------
__global__ __launch_bounds__(kBlock) void gemm1_kernel(
    const float* __restrict__ X,
    const float* __restrict__ W,
    _Float16* __restrict__ apws,
    unsigned int* __restrict__ maskws)
{
    __shared__ _Float16 WT[kA * kWTS];       // W^T [a][c], c-pads zeroed

    const int tid  = threadIdx.x;
    const int lane = tid & 63;
    const int wid  = tid >> 6;
    const int lm = lane & 15;
    const int lq = lane >> 4;
    const int ko = lq * 8;
    const size_t r0 = (size_t)blockIdx.x * kRowsPerBlock + wid * 16;

    // option bits (4 u32/lane): bit n = options[r0+4*lq+j][16n+lm] != 0.
    // Issued first; results not consumed until the mask store at the end,
    // so the full scan latency hides under staging + GEMM1.
    unsigned int obit[4];
    #pragma unroll
    for (int j = 0; j < 4; ++j) {
        const float* __restrict__ ox = X + (r0 + 4 * lq + j) * (size_t)(2 * kC);
        unsigned int b = 0;
        #pragma unroll
        for (int n = 0; n < 19; ++n) {
            const int c = 16 * n + lm;
            if (c < kC && ox[c] != 0.0f) b |= (1u << n);
        }
        obit[j] = b;
    }

    // stage W^T (f16) + zero pads
    for (int e = tid; e < kC * kA; e += kBlock) {
        const int c = e >> 5;
        const int a = e & 31;
        WT[a * kWTS + c] = (_Float16)W[e];
    }
    for (int e = tid; e < kA * (kWTS - kC); e += kBlock) {
        const int a = e / (kWTS - kC);
        const int c = kC + e % (kWTS - kC);
        WT[a * kWTS + c] = (_Float16)0.0f;
    }
    __syncthreads();

    const float* __restrict__ crow = X + (r0 + lm) * (size_t)(2 * kC) + kC;
    f32x4 acc0 = {0.f, 0.f, 0.f, 0.f};
    f32x4 acc1 = {0.f, 0.f, 0.f, 0.f};
    #pragma unroll
    for (int s = 0; s < 9; ++s) {   // K = 0..287
        const float4 u = *reinterpret_cast<const float4*>(crow + 32 * s + ko);
        const float4 v = *reinterpret_cast<const float4*>(crow + 32 * s + ko + 4);
        const half8 Af = { (_Float16)u.x, (_Float16)u.y, (_Float16)u.z, (_Float16)u.w,
                           (_Float16)v.x, (_Float16)v.y, (_Float16)v.z, (_Float16)v.w };
        const half8 B0 = *reinterpret_cast<const half8*>(&WT[lm * kWTS + 32 * s + ko]);
        const half8 B1 = *reinterpret_cast<const half8*>(&WT[(16 + lm) * kWTS + 32 * s + ko]);
        acc0 = __builtin_amdgcn_mfma_f32_16x16x32_f16(Af, B0, acc0, 0, 0, 0);
        acc1 = __builtin_amdgcn_mfma_f32_16x16x32_f16(Af, B1, acc1, 0, 0, 0);
    }
    {   // tail K = 288..299 (A zero-padded, WT pads zero)
        float av[8];
        #pragma unroll
        for (int j = 0; j < 8; ++j) {
            const int k = 288 + ko + j;
            av[j] = (k < kC) ? crow[k] : 0.0f;
        }
        const half8 Af = { (_Float16)av[0], (_Float16)av[1], (_Float16)av[2], (_Float16)av[3],
                           (_Float16)av[4], (_Float16)av[5], (_Float16)av[6], (_Float16)av[7] };
        const half8 B0 = *reinterpret_cast<const half8*>(&WT[lm * kWTS + 288 + ko]);
        const half8 B1 = *reinterpret_cast<const half8*>(&WT[(16 + lm) * kWTS + 288 + ko]);
        acc0 = __builtin_amdgcn_mfma_f32_16x16x32_f16(Af, B0, acc0, 0, 0, 0);
        acc1 = __builtin_amdgcn_mfma_f32_16x16x32_f16(Af, B1, acc1, 0, 0, 0);
    }

    // ap = acc + 1 -> f16 -> ws (row-major 64B rows); masks in B's exact layout
    #pragma unroll
    for (int j = 0; j < 4; ++j) {
        const size_t base = (r0 + 4 * lq + j) * (size_t)kA;
        apws[base + lm]      = (_Float16)(acc0[j] + 1.0f);
        apws[base + 16 + lm] = (_Float16)(acc1[j] + 1.0f);
    }
    #pragma unroll
    for (int j = 0; j < 4; ++j)
        maskws[(r0 + 4 * lq + j) * 16 + lm] = obit[j];
}

// ------- Kernel B: scores = ap @ W^T, masked log-softmax (no X reads) -------
__global__ __launch_bounds__(kBlock) void gemm2_kernel(
    const float* __restrict__ W,
    const _Float16* __restrict__ apws,
    const unsigned int* __restrict__ maskws,
    float* __restrict__ out)
{
    __shared__ _Float16 Wr[304 * kWrS];      // W [c][a], pad rows zeroed

    const int tid  = threadIdx.x;
    const int lane = tid & 63;
    const int wid  = tid >> 6;
    const int lm = lane & 15;
    const int lq = lane >> 4;
    const int ko = lq * 8;
    const size_t r0 = (size_t)blockIdx.x * kRowsPerBlock + wid * 16;

    // A-fragment straight from ws (16B) + 4 mask words; issued before staging.
    const half8 A2 = *reinterpret_cast<const half8*>(&apws[(r0 + lm) * (size_t)kA + ko]);
    unsigned int obit[4];
    #pragma unroll
    for (int j = 0; j < 4; ++j)
        obit[j] = maskws[(r0 + 4 * lq + j) * 16 + lm];

    // stage W rows (f16) + zero pad rows 300..303
    for (int e = tid; e < kC * kA; e += kBlock) {
        const int c = e >> 5;
        const int a = e & 31;
        Wr[c * kWrS + a] = (_Float16)W[e];
    }
    if (tid < 4 * kWrS) Wr[kC * kWrS + tid] = (_Float16)0.0f;
    __syncthreads();

    const f32x4 zz = {0.f, 0.f, 0.f, 0.f};

    // pass 1: row max (masked-off elements are 0 and participate, as in ref)
    f32x4 mj = {0.f, 0.f, 0.f, 0.f};   // every row has zeros (option density ~5%)
    #pragma unroll
    for (int n = 0; n < 19; ++n) {
        const half8 Bn = *reinterpret_cast<const half8*>(&Wr[(16 * n + lm) * kWrS + ko]);
        const f32x4 c4 = __builtin_amdgcn_mfma_f32_16x16x32_f16(A2, Bn, zz, 0, 0, 0);
        #pragma unroll
        for (int j = 0; j < 4; ++j) {
            const float x = ((obit[j] >> n) & 1u) ? c4[j] : 0.0f;
            mj[j] = fmaxf(mj[j], x);
        }
    }
    #pragma unroll
    for (int j = 0; j < 4; ++j) mj[j] = rmax16(mj[j]);

    // pass 2: S = sum of s * exp(x - M*s)
    f32x4 Sj = {0.f, 0.f, 0.f, 0.f};
    #pragma unroll
    for (int n = 0; n < 19; ++n) {
        const half8 Bn = *reinterpret_cast<const half8*>(&Wr[(16 * n + lm) * kWrS + ko]);
        const f32x4 c4 = __builtin_amdgcn_mfma_f32_16x16x32_f16(A2, Bn, zz, 0, 0, 0);
        #pragma unroll
        for (int j = 0; j < 4; ++j) {
            const float x = ((obit[j] >> n) & 1u) ? c4[j] : 0.0f;
            const float sg = (x > 0.f ? 1.f : 0.f) - (x < 0.f ? 1.f : 0.f);
            Sj[j] += sg * __expf(fmaf(-mj[j], sg, x));
        }
    }
    f32x4 lse;
    #pragma unroll
    for (int j = 0; j < 4; ++j) lse[j] = __logf(rsum16(Sj[j]));

    // pass 3: out = s * (x - M*s - lse)
    #pragma unroll
    for (int n = 0; n < 19; ++n) {
        const half8 Bn = *reinterpret_cast<const half8*>(&Wr[(16 * n + lm) * kWrS + ko]);
        const f32x4 c4 = __builtin_amdgcn_mfma_f32_16x16x32_f16(A2, Bn, zz, 0, 0, 0);
        const int c = 16 * n + lm;
        if (c < kC) {
            #pragma unroll
            for (int j = 0; j < 4; ++j) {
                const float x = ((obit[j] >> n) & 1u) ? c4[j] : 0.0f;
                const float sg = (x > 0.f ? 1.f : 0.f) - (x < 0.f ? 1.f : 0.f);
                out[(r0 + 4 * lq + j) * (size_t)kC + c] = sg * (fmaf(-mj[j], sg, x) - lse[j]);
            }
        }
    }
}

extern "C" void kernel_launch(void* const* d_in, const int* in_sizes, int n_in,
                              void* d_out, int out_size, void* d_ws, size_t ws_size,
                              hipStream_t stream) {
    const float* X = (const float*)d_in[0];
    const float* W = (const float*)d_in[1];
    float* out = (float*)d_out;
    _Float16* apws = (_Float16*)d_ws;                                  // 4 MiB
    unsigned int* maskws = (unsigned int*)((char*)d_ws + (4u << 20));  // 4 MiB
    dim3 grid(kB / kRowsPerBlock);           // 512 blocks
    dim3 block(kBlock);                      // 512 threads
    hipLaunchKernelGGL(gemm1_kernel, grid, block, 0, stream, X, W, apws, maskws);
    hipLaunchKernelGGL(gemm2_kernel, grid, block, 0, stream, W, apws, maskws, out);
}